// Round 10
// baseline (631.089 us; speedup 1.0000x reference)
//
#include <hip/hip_runtime.h>
#include <hip/hip_bf16.h>
#include <math.h>

#define NN 4096
#define EE 65536
#define NS 8192
#define NFEAT 1280
#define NHID 512
#define DFF 2048

typedef unsigned short u16;
typedef unsigned int u32;
typedef __attribute__((ext_vector_type(8))) short bf16x8;
typedef __attribute__((ext_vector_type(4))) float f32x4;
#define MFMA16(A,B,C) __builtin_amdgcn_mfma_f32_16x16x32_bf16(A,B,C,0,0,0)
#define GAS __attribute__((address_space(1)))
#define LAS __attribute__((address_space(3)))

#define SCL 0.18033688011112042f   // 0.125 * log2(e)  (softmax in exp2 domain)
#define THR 11.541560327111707f    // 8 * log2(e)

// ---------------- workspace offsets (in floats) ----------------
static const size_t OFF_A   = 0ull;          // 8,388,608  : SCb / FFb / GC2-in
static const size_t OFF_HP  = 8388608ull;    // 4,194,304  : gemm outputs (fp32 or bf16)
static const size_t OFF_X   = 12582912ull;   // 4,194,304  : fp32 encoder state
static const size_t OFF_XB  = 16777216ull;   // 2,097,152  : bf16 copy of X
static const size_t OFF_E   = 18874368ull;   // 6,291,456  : QKVb bf16 8192x1536, later AG2 fp32
static const size_t OFF_VT  = 25165824ull;   // 2,097,152  : Vtb bf16 [16][64][4096] (kappa-ordered keys)
static const size_t OFF_CTB = 27262976ull;   // 2,097,152  : CTb bf16 8192x512
static const size_t OFF_W1B = 29360128ull;
static const size_t OFF_IPB = 29687808ull;
static const size_t OFF_OPB = 30081024ull;
static const size_t OFF_F1B = 30212096ull;
static const size_t OFF_F2B = 30736384ull;
static const size_t OFF_W2B = 31260672ull;
static const size_t OFF_ME  = 31391744ull;
static const size_t OFF_DG  = 31408128ull;
static const size_t OFF_INT = 31424512ull;   // 164,096 ints (CSR)

// int-region offsets (in ints, from OFF_INT)
#define IH_S1 0
#define IH_D1 4096
#define IH_S2 8192
#define IH_D2 12288
#define IO_F1 16384
#define IO_F2 20608
#define IC_1  24832
#define IC_2  28928
#define IE_1  33024
#define IE_2  98560

__device__ __forceinline__ u16 f2b(float x) {
    u32 u = __float_as_uint(x);
    return (u16)((u + 0x7fffu + ((u >> 16) & 1u)) >> 16);
}
__device__ __forceinline__ float b_lo(u32 u) { return __uint_as_float(u << 16); }
__device__ __forceinline__ float b_hi(u32 u) { return __uint_as_float(u & 0xffff0000u); }

// ---------------- CSR build ----------------
__global__ __launch_bounds__(256) void k_hist(const int* __restrict__ s1, const int* __restrict__ d1,
                                              const int* __restrict__ s2, const int* __restrict__ d2,
                                              int* __restrict__ I)
{
    int e = blockIdx.x * 256 + threadIdx.x;
    if (e < EE) {
        atomicAdd(&I[IH_S1 + s1[e]], 1);
        atomicAdd(&I[IH_D1 + d1[e]], 1);
        atomicAdd(&I[IH_S2 + s2[e]], 1);
        atomicAdd(&I[IH_D2 + d2[e]], 1);
    }
}

__global__ __launch_bounds__(256) void k_deg_fin(const int* __restrict__ I, float* __restrict__ deg)
{
    int i = blockIdx.x * 256 + threadIdx.x;
    if (i < 4 * NN) deg[i] = rsqrtf(fmaxf((float)I[i], 1.0f));
}

__global__ __launch_bounds__(256) void k_scan(int* __restrict__ I)
{
    int b = blockIdx.x;
    const int* hist = I + (b ? IH_D2 : IH_D1);
    int* offs = I + (b ? IO_F2 : IO_F1);
    int* cur  = I + (b ? IC_2 : IC_1);
    __shared__ int part[256];
    int t = threadIdx.x;
    int base = t * 16;
    int loc[16];
    int s = 0;
#pragma unroll
    for (int i = 0; i < 16; ++i) { loc[i] = s; s += hist[base + i]; }
    part[t] = s;
    __syncthreads();
    if (t == 0) {
        int a = 0;
        for (int i = 0; i < 256; ++i) { int v = part[i]; part[i] = a; a += v; }
        offs[NN] = a;
    }
    __syncthreads();
    int p = part[t];
#pragma unroll
    for (int i = 0; i < 16; ++i) { offs[base + i] = p + loc[i]; cur[base + i] = p + loc[i]; }
}

__global__ __launch_bounds__(256) void k_fill(const int* __restrict__ s1, const int* __restrict__ d1,
                                              const int* __restrict__ s2, const int* __restrict__ d2,
                                              int* __restrict__ I)
{
    int e = blockIdx.x * 256 + threadIdx.x;
    if (e < EE) {
        int p1 = atomicAdd(&I[IC_1 + d1[e]], 1);
        I[IE_1 + p1] = s1[e];
        int p2 = atomicAdd(&I[IC_2 + d2[e]], 1);
        I[IE_2 + p2] = s2[e];
    }
}

// ---------------- fp32 -> bf16 convert ----------------
__global__ __launch_bounds__(256) void k_cvt(const float* __restrict__ src, u16* __restrict__ dst, int n)
{
    int i = (blockIdx.x * 256 + threadIdx.x) * 8;
    if (i >= n) return;
    float4 a = *(const float4*)&src[i];
    float4 b = *(const float4*)&src[i + 4];
    uint4 o;
    o.x = (u32)f2b(a.x) | ((u32)f2b(a.y) << 16);
    o.y = (u32)f2b(a.z) | ((u32)f2b(a.w) << 16);
    o.z = (u32)f2b(b.x) | ((u32)f2b(b.y) << 16);
    o.w = (u32)f2b(b.z) | ((u32)f2b(b.w) << 16);
    *(uint4*)&dst[i] = o;
}

// ---------------- row scale -> bf16 out (stacked 2-graph) ----------------
__global__ __launch_bounds__(256) void k_scale_bf(const float* __restrict__ in1, const float* __restrict__ in2,
                                                  const float* __restrict__ sc1, const float* __restrict__ sc2,
                                                  u16* __restrict__ out, int ncol)
{
    int quads = ncol >> 2;
    long long idx = (long long)blockIdx.x * 256 + threadIdx.x;
    if (idx >= (long long)NS * quads) return;
    int r  = (int)(idx / quads);
    int cq = (int)(idx % quads) * 4;
    const float* in; const float* sc; int rr;
    if (r < NN) { in = in1; sc = sc1; rr = r; } else { in = in2; sc = sc2; rr = r - NN; }
    float4 v = *(const float4*)&in[(size_t)rr * ncol + cq];
    float s = sc[rr];
    uint2 o;
    o.x = (u32)f2b(v.x * s) | ((u32)f2b(v.y * s) << 16);
    o.y = (u32)f2b(v.z * s) | ((u32)f2b(v.w * s) << 16);
    *(uint2*)&out[(size_t)r * ncol + cq] = o;
}

// ---------------- bf16 MFMA GEMM (m97 structure: global_load_lds width-16, 2 barriers/K-step) ----
// BN=128: 4 waves as 2x2 (64x64 each); BN=64: 4 waves as 4x1 (32x64 each).
// qcols: columns < qcols are scaled by SCL in the epilogue (qkv GEMM q-part).
template<int BN>
__global__ __launch_bounds__(256) void k_gemm_bf(const u16* __restrict__ A, const u16* __restrict__ W,
                                                 const float* __restrict__ bias, float* __restrict__ Cf,
                                                 u16* __restrict__ Cb, int M, int N, int K, int relu,
                                                 int qcols)
{
    constexpr int RM = (BN == 128) ? 4 : 2;   // row frags per wave
    __shared__ u16 As[128 * 32];
    __shared__ u16 Bs[BN * 32];
    int t = threadIdx.x;
    int w = t >> 6, L = t & 63;
    int lm = L & 15, lq = L >> 4;
    int wr = (BN == 128) ? (w >> 1) : w;
    int wc = (BN == 128) ? (w & 1) : 0;
    int row0 = blockIdx.y * 128, col0 = blockIdx.x * BN;
    f32x4 acc[RM][4];
#pragma unroll
    for (int i = 0; i < RM; ++i)
#pragma unroll
        for (int j = 0; j < 4; ++j) acc[i][j] = (f32x4){0.f, 0.f, 0.f, 0.f};

    // glds sources: instr j covers LDS rows (w*2+j)*16 + L/4, col-elems (L&3)*8
    const u16* As0 = &A[(size_t)(row0 + (w * 2) * 16 + (L >> 2)) * K + (L & 3) * 8];
    const u16* As1 = As0 + (size_t)16 * K;
    const u16* Bs0 = &W[(size_t)(col0 + ((BN == 128) ? (w * 2) * 16 : w * 16) + (L >> 2)) * K + (L & 3) * 8];
    const u16* Bs1 = Bs0 + (size_t)16 * K;
    u16* AsW = &As[(w * 2) * 512];
    u16* BsW = (BN == 128) ? &Bs[(w * 2) * 512] : &Bs[w * 512];

    for (int k0 = 0; k0 < K; k0 += 32) {
        if (k0) __syncthreads();   // all reads of previous tile done
        __builtin_amdgcn_global_load_lds((const GAS void*)(As0 + k0), (LAS void*)(LAS char*)AsW, 16, 0, 0);
        __builtin_amdgcn_global_load_lds((const GAS void*)(As1 + k0), (LAS void*)((LAS char*)AsW + 1024), 16, 0, 0);
        __builtin_amdgcn_global_load_lds((const GAS void*)(Bs0 + k0), (LAS void*)(LAS char*)BsW, 16, 0, 0);
        if constexpr (BN == 128)
            __builtin_amdgcn_global_load_lds((const GAS void*)(Bs1 + k0), (LAS void*)((LAS char*)BsW + 1024), 16, 0, 0);
        __syncthreads();           // vmcnt drained -> tile in LDS
        bf16x8 af[RM], bw[4];
#pragma unroll
        for (int i = 0; i < RM; ++i)
            af[i] = *(const bf16x8*)&As[(wr * (RM * 16) + i * 16 + lm) * 32 + lq * 8];
#pragma unroll
        for (int j = 0; j < 4; ++j)
            bw[j] = *(const bf16x8*)&Bs[(wc * 64 + j * 16 + lm) * 32 + lq * 8];
#pragma unroll
        for (int i = 0; i < RM; ++i)
#pragma unroll
            for (int j = 0; j < 4; ++j)
                acc[i][j] = MFMA16(af[i], bw[j], acc[i][j]);
    }

#pragma unroll
    for (int i = 0; i < RM; ++i) {
        int row = row0 + wr * (RM * 16) + i * 16 + lq * 4;
#pragma unroll
        for (int j = 0; j < 4; ++j) {
            int col = col0 + wc * 64 + j * 16 + lm;
            float bv = bias ? bias[col] : 0.0f;
            float cs = (col < qcols) ? SCL : 1.0f;
#pragma unroll
            for (int r = 0; r < 4; ++r) {
                float v = acc[i][j][r] + bv;
                if (relu) v = fmaxf(v, 0.0f);
                v *= cs;
                size_t off = (size_t)(row + r) * N + col;
                if (Cb) Cb[off] = f2b(v);
                else    Cf[off] = v;
            }
        }
    }
}

// ---------------- CSR gather (bf16 in) + GC finalize ----------------
__global__ __launch_bounds__(256) void k_gather_bf(const u16* __restrict__ hp, const int* __restrict__ I,
                                                   const float* __restrict__ din1, const float* __restrict__ din2,
                                                   const float* __restrict__ bias,
                                                   float* __restrict__ xout, u16* __restrict__ xb)
{
    int r = blockIdx.x, c = threadIdx.x;
    int g = r >> 12, rl = r & (NN - 1);
    const int* off = I + (g ? IO_F2 : IO_F1);
    const int* eid = I + (g ? IE_2 : IE_1);
    int beg = off[rl], end = off[rl + 1];
    const u16* base = hp + ((size_t)g << 12) * NHID;
    float a0 = 0.f, a1 = 0.f;
    for (int i = beg; i < end; ++i) {
        u32 v = ((const u32*)(base + (size_t)eid[i] * NHID))[c];
        a0 += b_lo(v);
        a1 += b_hi(v);
    }
    float s = (g ? din2 : din1)[rl];
    float2 bv = *(const float2*)&bias[c * 2];
    float v0 = fmaxf(fmaf(a0, s, bv.x), 0.f);
    float v1 = fmaxf(fmaf(a1, s, bv.y), 0.f);
    size_t o = (size_t)r * NHID + c * 2;
    if (xout) *(float2*)&xout[o] = make_float2(v0, v1);
    if (xb) *(u32*)&xb[o] = (u32)f2b(v0) | ((u32)f2b(v1) << 16);
}

// ---------------- V transpose (keys written in kappa order within each 64-tile) ----------------
// kappa = (key&15)*4 + (key>>4)  <=>  key = (kappa&3)*16 + (kappa>>2)
__global__ __launch_bounds__(256) void k_vtrans(const u16* __restrict__ qkvb, u16* __restrict__ vtb)
{
    __shared__ u16 tile[64][65];
    int t = threadIdx.x;
    int kt = blockIdx.x, h = blockIdx.y, g = blockIdx.z;
    int k0 = kt * 64;
    size_t gbase = (size_t)g * NN;
#pragma unroll
    for (int p = 0; p < 4; ++p) {
        int kl = p * 16 + (t >> 4);
        int d  = (t & 15) * 4;
        uint2 v = *(const uint2*)&qkvb[(gbase + k0 + kl) * 1536 + 1024 + h * 64 + d];
        tile[kl][d + 0] = (u16)(v.x & 0xffff);
        tile[kl][d + 1] = (u16)(v.x >> 16);
        tile[kl][d + 2] = (u16)(v.y & 0xffff);
        tile[kl][d + 3] = (u16)(v.y >> 16);
    }
    __syncthreads();
#pragma unroll
    for (int p = 0; p < 4; ++p) {
        int dl = p * 16 + (t >> 4);
        int kap = (t & 15) * 4;           // kappa base; kappa+e -> local key e*16 + (t&15)
        u16 v0 = tile[(t & 15) + 0][dl];
        u16 v1 = tile[(t & 15) + 16][dl];
        u16 v2 = tile[(t & 15) + 32][dl];
        u16 v3 = tile[(t & 15) + 48][dl];
        uint2 o;
        o.x = (u32)v0 | ((u32)v1 << 16);
        o.y = (u32)v2 | ((u32)v3 << 16);
        *(uint2*)&vtb[((size_t)(g * 8 + h) * 64 + dl) * (size_t)NN + k0 + kap] = o;
    }
}

// ---------------- MFMA flash attention v6 ----------------
// 4 waves/block, 16 q-rows/wave (64 q/block), 64-key tiles, double-buffered
// global_load_lds; 40KB LDS -> 4 blocks/CU (16 waves). All LDS rows 128B with
// (row&7)<<4 XOR swizzle. Keys kappa-permuted. Q pre-scaled by SCL in qkv GEMM.
__global__ __launch_bounds__(256, 4) void k_attn(const u16* __restrict__ qkv,
                                                 const u16* __restrict__ vt,
                                                 u16* __restrict__ ctb)
{
    __shared__ __align__(16) u16 Kl[2][64 * 64];   // [rho][d]   rho holds key perm(rho)
    __shared__ __align__(16) u16 Vl[2][64 * 64];   // [d][kappa]
    __shared__ __align__(16) u16 Pl[4][16 * 64];   // per-wave [q][kappa]
    int t = threadIdx.x;
    int w = t >> 6, L = t & 63;
    int lm = L & 15, lq = L >> 4;
    int qt = blockIdx.x, h = blockIdx.y, g = blockIdx.z;
    size_t gbase = (size_t)g * NN;
    int q0 = qt * 64 + w * 16;

    const u16* kbase = &qkv[gbase * 1536 + 512 + h * 64];
    const u16* vbase = &vt[(size_t)(g * 8 + h) * 64 * (size_t)NN];

    // staging: instr j covers LDS rows rho = (w*2+j)*8 + L/8, byte (L&7)*16 ^ (rho&7)<<4
    int srcb = ((L & 7) * 16) ^ ((L >> 3) << 4);          // (rho&7) == L>>3
    int rho0 = (w * 2) * 8 + (L >> 3);
    int rho1 = rho0 + 8;
    int kp0 = (rho0 & 15) * 4 + (rho0 >> 4);              // perm(rho): global key row
    int kp1 = (rho1 & 15) * 4 + (rho1 >> 4);
    const u16* kg0 = &kbase[(size_t)kp0 * 1536 + (srcb >> 1)];
    const u16* kg1 = &kbase[(size_t)kp1 * 1536 + (srcb >> 1)];
    const u16* vg0 = &vbase[(size_t)rho0 * NN + (srcb >> 1)];
    const u16* vg1 = &vbase[(size_t)rho1 * NN + (srcb >> 1)];
    u16* Pw = &Pl[w][0];

    // Q A-frags (16 rows; q pre-scaled by SCL)
    const u16* qp = &qkv[(gbase + q0 + lm) * 1536 + h * 64 + lq * 8];
    bf16x8 qa0 = *(const bf16x8*)qp;
    bf16x8 qa1 = *(const bf16x8*)(qp + 32);

    f32x4 ctx[4];
#pragma unroll
    for (int n = 0; n < 4; ++n) ctx[n] = (f32x4){0.f, 0.f, 0.f, 0.f};
    float m[4], lsum[4];
#pragma unroll
    for (int r = 0; r < 4; ++r) { m[r] = -1e30f; lsum[r] = 0.0f; }

    // prologue: stage tile 0 into buf 0
    __builtin_amdgcn_global_load_lds((const GAS void*)kg0, (LAS void*)((LAS char*)&Kl[0][0] + (w * 2) * 1024), 16, 0, 0);
    __builtin_amdgcn_global_load_lds((const GAS void*)kg1, (LAS void*)((LAS char*)&Kl[0][0] + (w * 2 + 1) * 1024), 16, 0, 0);
    __builtin_amdgcn_global_load_lds((const GAS void*)vg0, (LAS void*)((LAS char*)&Vl[0][0] + (w * 2) * 1024), 16, 0, 0);
    __builtin_amdgcn_global_load_lds((const GAS void*)vg1, (LAS void*)((LAS char*)&Vl[0][0] + (w * 2 + 1) * 1024), 16, 0, 0);
    __syncthreads();

    int cur = 0;
    for (int t0 = 0; t0 < NN; t0 += 64) {
        if (t0 + 64 < NN) {
            size_t ko = (size_t)(t0 + 64) * 1536;
            __builtin_amdgcn_global_load_lds((const GAS void*)(kg0 + ko), (LAS void*)((LAS char*)&Kl[cur ^ 1][0] + (w * 2) * 1024), 16, 0, 0);
            __builtin_amdgcn_global_load_lds((const GAS void*)(kg1 + ko), (LAS void*)((LAS char*)&Kl[cur ^ 1][0] + (w * 2 + 1) * 1024), 16, 0, 0);
            __builtin_amdgcn_global_load_lds((const GAS void*)(vg0 + t0 + 64), (LAS void*)((LAS char*)&Vl[cur ^ 1][0] + (w * 2) * 1024), 16, 0, 0);
            __builtin_amdgcn_global_load_lds((const GAS void*)(vg1 + t0 + 64), (LAS void*)((LAS char*)&Vl[cur ^ 1][0] + (w * 2 + 1) * 1024), 16, 0, 0);
        }
        const char* Kc = (const char*)&Kl[cur][0];
        const char* Vc = (const char*)&Vl[cur][0];
        int sw = (lm & 7) << 4;

        // QK^T (already in exp2 units); lane (lm,lq) col lm of kc-mfma = key kappa=lm*4+kc
        f32x4 s[4];
        __builtin_amdgcn_s_setprio(1);
#pragma unroll
        for (int kc = 0; kc < 4; ++kc) {
            const char* rp = Kc + (kc * 16 + lm) * 128;
            bf16x8 kb0 = *(const bf16x8*)(rp + ((lq * 16) ^ sw));
            bf16x8 kb1 = *(const bf16x8*)(rp + ((64 + lq * 16) ^ sw));
            f32x4 z = (f32x4){0.f, 0.f, 0.f, 0.f};
            z = MFMA16(qa0, kb0, z);
            z = MFMA16(qa1, kb1, z);
            s[kc] = z;
        }
        __builtin_amdgcn_s_setprio(0);

        // deferred-max check
        float dmax = -1e30f;
#pragma unroll
        for (int r = 0; r < 4; ++r) {
            float a = fmaxf(fmaxf(s[0][r], s[1][r]), fmaxf(s[2][r], s[3][r]));
            dmax = fmaxf(dmax, a - m[r]);
        }
        if (__any(dmax > THR)) {
#pragma unroll
            for (int r = 0; r < 4; ++r) {
                float mr = fmaxf(fmaxf(s[0][r], s[1][r]), fmaxf(s[2][r], s[3][r]));
                mr = fmaxf(mr, __shfl_xor(mr, 1));
                mr = fmaxf(mr, __shfl_xor(mr, 2));
                mr = fmaxf(mr, __shfl_xor(mr, 4));
                mr = fmaxf(mr, __shfl_xor(mr, 8));
                float mn = fmaxf(m[r], mr);
                float corr = exp2f(m[r] - mn);
                m[r] = mn;
                lsum[r] *= corr;
#pragma unroll
                for (int n = 0; n < 4; ++n) ctx[n][r] *= corr;
            }
        }
        // fast path: exp2, per-lane l partial, packed P -> LDS
#pragma unroll
        for (int r = 0; r < 4; ++r) {
            float mq = m[r];
            float p0 = exp2f(s[0][r] - mq);
            float p1 = exp2f(s[1][r] - mq);
            float p2 = exp2f(s[2][r] - mq);
            float p3 = exp2f(s[3][r] - mq);
            lsum[r] += (p0 + p1) + (p2 + p3);
            int row = lq * 4 + r;
            __hip_bfloat162 c0 = __float22bfloat162_rn(make_float2(p0, p1));
            __hip_bfloat162 c1 = __float22bfloat162_rn(make_float2(p2, p3));
            uint2 pv;
            pv.x = *(u32*)&c0;
            pv.y = *(u32*)&c1;
            *(uint2*)((char*)Pw + row * 128 + ((lm * 8) ^ ((row & 7) << 4))) = pv;
        }

        // PV over kappa-ordered keys
        __builtin_amdgcn_s_setprio(1);
        {
            const char* pr = (const char*)Pw + lm * 128;
            bf16x8 pa0 = *(const bf16x8*)(pr + ((lq * 16) ^ sw));
            bf16x8 pa1 = *(const bf16x8*)(pr + ((64 + lq * 16) ^ sw));
#pragma unroll
            for (int n = 0; n < 4; ++n) {
                const char* vr = Vc + (n * 16 + lm) * 128;
                bf16x8 vb0 = *(const bf16x8*)(vr + ((lq * 16) ^ sw));
                bf16x8 vb1 = *(const bf16x8*)(vr + ((64 + lq * 16) ^ sw));
                ctx[n] = MFMA16(pa0, vb0, ctx[n]);
                ctx[n] = MFMA16(pa1, vb1, ctx[n]);
            }
        }
        __builtin_amdgcn_s_setprio(0);

        __syncthreads();   // drains prefetch (vmcnt0) + LDS reuse fence
        cur ^= 1;
    }

    // epilogue
    float inv[4];
#pragma unroll
    for (int r = 0; r < 4; ++r) {
        float lr = lsum[r];
        lr += __shfl_xor(lr, 1);
        lr += __shfl_xor(lr, 2);
        lr += __shfl_xor(lr, 4);
        lr += __shfl_xor(lr, 8);
        inv[r] = 1.0f / lr;
    }
#pragma unroll
    for (int n = 0; n < 4; ++n)
#pragma unroll
        for (int r = 0; r < 4; ++r) {
            int row = q0 + lq * 4 + r;
            int col = h * 64 + n * 16 + lm;
            ctb[(gbase + row) * NHID + col] = f2b(ctx[n][r] * inv[r]);
        }
}

// ---------------- fused residual-add + LayerNorm (+optional row-scale) + bf16 out ----------------
__global__ __launch_bounds__(256) void k_add_ln(const float* __restrict__ x, const float* __restrict__ y,
                                                const float* __restrict__ g, const float* __restrict__ bb,
                                                float* __restrict__ xout, u16* __restrict__ xb,
                                                const float* __restrict__ sc1, const float* __restrict__ sc2)
{
    int r = blockIdx.x, tid = threadIdx.x;
    int c = tid * 2;
    float2 xv = *(const float2*)&x[(size_t)r * NHID + c];
    float2 yv = *(const float2*)&y[(size_t)r * NHID + c];
    float a0 = xv.x + yv.x, a1 = xv.y + yv.y;
    float s = a0 + a1;
    float qs = a0 * a0 + a1 * a1;
#pragma unroll
    for (int off = 32; off > 0; off >>= 1) {
        s  += __shfl_xor(s, off);
        qs += __shfl_xor(qs, off);
    }
    __shared__ float ss[4], qq[4];
    int w = tid >> 6;
    if ((tid & 63) == 0) { ss[w] = s; qq[w] = qs; }
    __syncthreads();
    s  = ss[0] + ss[1] + ss[2] + ss[3];
    qs = qq[0] + qq[1] + qq[2] + qq[3];
    float mu  = s * (1.0f / NHID);
    float var = qs * (1.0f / NHID) - mu * mu;
    float rs = rsqrtf(var + 1e-5f);
    float2 gv = *(const float2*)&g[c];
    float2 bv = *(const float2*)&bb[c];
    float o0 = (a0 - mu) * rs * gv.x + bv.x;
    float o1 = (a1 - mu) * rs * gv.y + bv.y;
    if (xout) *(float2*)&xout[(size_t)r * NHID + c] = make_float2(o0, o1);
    float sc = 1.0f;
    if (sc1) sc = (r < NN) ? sc1[r] : sc2[r - NN];
    u32 o = (u32)f2b(o0 * sc) | ((u32)f2b(o1 * sc) << 16);
    *(u32*)&xb[(size_t)r * NHID + c] = o;
}

// ---------------- per-segment mean ----------------
__global__ __launch_bounds__(512) void k_seg_mean(const float* __restrict__ h, float* __restrict__ means)
{
    int b = blockIdx.x;
    int st = blockIdx.y;
    int col = threadIdx.x;
    const float* hp = &h[((size_t)st * NN + (size_t)b * 256) * NHID + col];
    float acc = 0.0f;
    for (int i = 0; i < 256; ++i) acc += hp[(size_t)i * NHID];
    means[((size_t)st * 16 + b) * NHID + col] = acc * (1.0f / 256.0f);
}

// ---------------- MLP head + softmax ----------------
__global__ __launch_bounds__(256) void k_head(const float* __restrict__ means,
                                              const float* __restrict__ l1w, const float* __restrict__ l1b,
                                              const float* __restrict__ l2w, const float* __restrict__ l2b,
                                              const float* __restrict__ l3w, const float* __restrict__ l3b,
                                              float* __restrict__ out)
{
    __shared__ float hg[512];
    __shared__ float t1[512];
    __shared__ float t2[128];
    int b = blockIdx.x;
    int t = threadIdx.x;
    hg[t]       = means[b * 512 + t]       * means[(16 + b) * 512 + t];
    hg[t + 256] = means[b * 512 + t + 256] * means[(16 + b) * 512 + t + 256];
    __syncthreads();
#pragma unroll
    for (int o = t; o < 512; o += 256) {
        const float* wr = &l1w[(size_t)o * 512];
        float acc = l1b[o];
        for (int k = 0; k < 512; k += 4) {
            float4 w = *(const float4*)&wr[k];
            acc = fmaf(hg[k], w.x, acc);
            acc = fmaf(hg[k + 1], w.y, acc);
            acc = fmaf(hg[k + 2], w.z, acc);
            acc = fmaf(hg[k + 3], w.w, acc);
        }
        t1[o] = acc;
    }
    __syncthreads();
    if (t < 128) {
        const float* wr = &l2w[(size_t)t * 512];
        float acc = l2b[t];
        for (int k = 0; k < 512; k += 4) {
            float4 w = *(const float4*)&wr[k];
            acc = fmaf(t1[k], w.x, acc);
            acc = fmaf(t1[k + 1], w.y, acc);
            acc = fmaf(t1[k + 2], w.z, acc);
            acc = fmaf(t1[k + 3], w.w, acc);
        }
        t2[t] = acc;
    }
    __syncthreads();
    if (t < 64) {
        float p0 = t2[t] * l3w[t] + t2[t + 64] * l3w[t + 64];
        float p1 = t2[t] * l3w[128 + t] + t2[t + 64] * l3w[128 + t + 64];
#pragma unroll
        for (int off = 32; off > 0; off >>= 1) {
            p0 += __shfl_xor(p0, off);
            p1 += __shfl_xor(p1, off);
        }
        if (t == 0) {
            float v0 = p0 + l3b[0], v1 = p1 + l3b[1];
            float mx = fmaxf(v0, v1);
            float e0 = __expf(v0 - mx), e1 = __expf(v1 - mx);
            float inv = 1.0f / (e0 + e1);
            out[b * 2 + 0] = e0 * inv;
            out[b * 2 + 1] = e1 * inv;
        }
    }
}

// ---------------- launch ----------------
extern "C" void kernel_launch(void* const* d_in, const int* in_sizes, int n_in,
                              void* d_out, int out_size, void* d_ws, size_t ws_size,
                              hipStream_t stream)
{
    const float* fea1 = (const float*)d_in[0];
    const float* fea2 = (const float*)d_in[1];
    const int* src1 = (const int*)d_in[2];
    const int* dst1 = (const int*)d_in[3];
    const int* src2 = (const int*)d_in[4];
    const int* dst2 = (const int*)d_in[5];
    const float* W1 = (const float*)d_in[9];
    const float* b1 = (const float*)d_in[10];
    const float* W2 = (const float*)d_in[11];
    const float* b2 = (const float*)d_in[12];
    const float* in_proj_w = (const float*)d_in[13];
    const float* in_proj_b = (const float*)d_in[14];
    const float* out_proj_w = (const float*)d_in[15];
    const float* out_proj_b = (const float*)d_in[16];
    const float* ln1_g = (const float*)d_in[17];
    const float* ln1_b = (const float*)d_in[18];
    const float* ln2_g = (const float*)d_in[19];
    const float* ln2_b = (const float*)d_in[20];
    const float* ff1_w = (const float*)d_in[21];
    const float* ff1_b = (const float*)d_in[22];
    const float* ff2_w = (const float*)d_in[23];
    const float* ff2_b = (const float*)d_in[24];
    const float* l1_w = (const float*)d_in[25];
    const float* l1_b = (const float*)d_in[26];
    const float* l2_w = (const float*)d_in[27];
    const float* l2_b = (const float*)d_in[28];
    const float* l3_w = (const float*)d_in[29];
    const float* l3_b = (const float*)d_in[30];

    float* ws = (float*)d_ws;
    u16*  Ab   = (u16*)(ws + OFF_A);
    float* HP  = ws + OFF_HP;
    u16*  HPb  = (u16*)(ws + OFF_HP);
    float* X   = ws + OFF_X;
    u16*  Xb   = (u16*)(ws + OFF_XB);
    u16*  QKVb = (u16*)(ws + OFF_E);
    float* AG2 = ws + OFF_E;
    u16*  Vtb  = (u16*)(ws + OFF_VT);
    u16*  CTb  = (u16*)(ws + OFF_CTB);
    u16*  W1b  = (u16*)(ws + OFF_W1B);
    u16*  IPb  = (u16*)(ws + OFF_IPB);
    u16*  OPb  = (u16*)(ws + OFF_OPB);
    u16*  F1b  = (u16*)(ws + OFF_F1B);
    u16*  F2b  = (u16*)(ws + OFF_F2B);
    u16*  W2b  = (u16*)(ws + OFF_W2B);
    float* ME  = ws + OFF_ME;
    float* DG  = ws + OFF_DG;
    int*   I   = (int*)(ws + OFF_INT);
    float* dout1 = DG;
    float* din1  = DG + NN;
    float* dout2 = DG + 2 * NN;
    float* din2  = DG + 3 * NN;

    hipMemsetAsync(I, 0, 4 * NN * sizeof(int), stream);

    // CSR build + degrees
    k_hist<<<EE / 256, 256, 0, stream>>>(src1, dst1, src2, dst2, I);
    k_deg_fin<<<(4 * NN) / 256, 256, 0, stream>>>(I, DG);
    k_scan<<<2, 256, 0, stream>>>(I);
    k_fill<<<EE / 256, 256, 0, stream>>>(src1, dst1, src2, dst2, I);

    // weight conversions
    k_cvt<<<(NHID * NFEAT / 8 + 255) / 256, 256, 0, stream>>>(W1, W1b, NHID * NFEAT);
    k_cvt<<<(3 * NHID * NHID / 8 + 255) / 256, 256, 0, stream>>>(in_proj_w, IPb, 3 * NHID * NHID);
    k_cvt<<<(NHID * NHID / 8 + 255) / 256, 256, 0, stream>>>(out_proj_w, OPb, NHID * NHID);
    k_cvt<<<(DFF * NHID / 8 + 255) / 256, 256, 0, stream>>>(ff1_w, F1b, DFF * NHID);
    k_cvt<<<(NHID * DFF / 8 + 255) / 256, 256, 0, stream>>>(ff2_w, F2b, NHID * DFF);
    k_cvt<<<(NHID * NHID / 8 + 255) / 256, 256, 0, stream>>>(W2, W2b, NHID * NHID);

    // GC1: scale -> gemm (bf16 out) -> CSR gather
    {
        long long tq = (long long)NS * (NFEAT / 4);
        k_scale_bf<<<(int)((tq + 255) / 256), 256, 0, stream>>>(fea1, fea2, dout1, dout2, Ab, NFEAT);
    }
    k_gemm_bf<64><<<dim3(NHID / 64, NS / 128), 256, 0, stream>>>(Ab, W1b, nullptr, nullptr, HPb, NS, NHID, NFEAT, 0, 0);
    k_gather_bf<<<NS, 256, 0, stream>>>(HPb, I, din1, din2, b1, X, Xb);

    // encoder (q-part of qkv pre-scaled by SCL in the GEMM epilogue)
    k_gemm_bf<128><<<dim3(1536 / 128, NS / 128), 256, 0, stream>>>(Xb, IPb, in_proj_b, nullptr, QKVb, NS, 1536, NHID, 0, NHID);
    k_vtrans<<<dim3(NN / 64, 8, 2), 256, 0, stream>>>(QKVb, Vtb);
    k_attn<<<dim3(NN / 64, 8, 2), 256, 0, stream>>>(QKVb, Vtb, CTb);
    k_gemm_bf<64><<<dim3(NHID / 64, NS / 128), 256, 0, stream>>>(CTb, OPb, out_proj_b, HP, nullptr, NS, NHID, NHID, 0, 0);
    k_add_ln<<<NS, 256, 0, stream>>>(X, HP, ln1_g, ln1_b, X, Xb, nullptr, nullptr);
    k_gemm_bf<128><<<dim3(DFF / 128, NS / 128), 256, 0, stream>>>(Xb, F1b, ff1_b, nullptr, Ab, NS, DFF, NHID, 1, 0);
    k_gemm_bf<64><<<dim3(NHID / 64, NS / 128), 256, 0, stream>>>(Ab, F2b, ff2_b, HP, nullptr, NS, NHID, DFF, 0, 0);
    // LN2 fused with GC2 pre-scale
    k_add_ln<<<NS, 256, 0, stream>>>(X, HP, ln2_g, ln2_b, nullptr, Ab, dout1, dout2);

    // GC2
    k_gemm_bf<64><<<dim3(NHID / 64, NS / 128), 256, 0, stream>>>(Ab, W2b, nullptr, nullptr, HPb, NS, NHID, NHID, 0, 0);
    k_gather_bf<<<NS, 256, 0, stream>>>(HPb, I, din1, din2, b2, AG2, nullptr);

    // readout
    k_seg_mean<<<dim3(16, 2), 512, 0, stream>>>(AG2, ME);
    k_head<<<16, 256, 0, stream>>>(ME, l1_w, l1_b, l2_w, l2_b, l3_w, l3_b, (float*)d_out);
}

// Round 12
// 613.446 us; speedup vs baseline: 1.0288x; 1.0288x over previous
//
#include <hip/hip_runtime.h>
#include <hip/hip_bf16.h>
#include <math.h>

#define NN 4096
#define EE 65536
#define NS 8192
#define NFEAT 1280
#define NHID 512
#define DFF 2048

typedef unsigned short u16;
typedef unsigned int u32;
typedef __attribute__((ext_vector_type(8))) short bf16x8;
typedef __attribute__((ext_vector_type(4))) float f32x4;
#define MFMA16(A,B,C) __builtin_amdgcn_mfma_f32_16x16x32_bf16(A,B,C,0,0,0)
#define GAS __attribute__((address_space(1)))
#define LAS __attribute__((address_space(3)))

#define SCL 0.18033688011112042f   // 0.125 * log2(e)  (softmax in exp2 domain)
#define THR 11.541560327111707f    // 8 * log2(e)

// ---------------- workspace offsets (in floats) ----------------
static const size_t OFF_A   = 0ull;          // 8,388,608  : SCb / FFb / GC2-in
static const size_t OFF_HP  = 8388608ull;    // 4,194,304  : gemm outputs (fp32 or bf16)
static const size_t OFF_X   = 12582912ull;   // 4,194,304  : fp32 encoder state
static const size_t OFF_XB  = 16777216ull;   // 2,097,152  : bf16 copy of X
static const size_t OFF_E   = 18874368ull;   // 6,291,456  : QKVb bf16 8192x1536, later AG2 fp32
static const size_t OFF_VT  = 25165824ull;   // 2,097,152  : Vtb bf16 [16][64][4096] (kappa-ordered keys)
static const size_t OFF_CTB = 27262976ull;   // 2,097,152  : CTb bf16 8192x512
static const size_t OFF_W1B = 29360128ull;
static const size_t OFF_IPB = 29687808ull;
static const size_t OFF_OPB = 30081024ull;
static const size_t OFF_F1B = 30212096ull;
static const size_t OFF_F2B = 30736384ull;
static const size_t OFF_W2B = 31260672ull;
static const size_t OFF_ME  = 31391744ull;
static const size_t OFF_DG  = 31408128ull;
static const size_t OFF_INT = 31424512ull;   // 164,096 ints (CSR)

// int-region offsets (in ints, from OFF_INT)
#define IH_S1 0
#define IH_D1 4096
#define IH_S2 8192
#define IH_D2 12288
#define IO_F1 16384
#define IO_F2 20608
#define IC_1  24832
#define IC_2  28928
#define IE_1  33024
#define IE_2  98560

// weight-conversion segment sizes (elements)
#define CV1 655360            // W1  512*1280
#define CV2 1441792           // +in_proj 3*512*512
#define CV3 1703936           // +out_proj 512*512
#define CV4 2752512           // +ff1 2048*512
#define CV5 3801088           // +ff2 512*2048
#define CV6 4063232           // +W2 512*512

__device__ __forceinline__ u16 f2b(float x) {
    u32 u = __float_as_uint(x);
    return (u16)((u + 0x7fffu + ((u >> 16) & 1u)) >> 16);
}
__device__ __forceinline__ float b_lo(u32 u) { return __uint_as_float(u << 16); }
__device__ __forceinline__ float b_hi(u32 u) { return __uint_as_float(u & 0xffff0000u); }

// ---------------- CSR build ----------------
__global__ __launch_bounds__(256) void k_hist(const int* __restrict__ s1, const int* __restrict__ d1,
                                              const int* __restrict__ s2, const int* __restrict__ d2,
                                              int* __restrict__ I)
{
    int e = blockIdx.x * 256 + threadIdx.x;
    if (e < EE) {
        atomicAdd(&I[IH_S1 + s1[e]], 1);
        atomicAdd(&I[IH_D1 + d1[e]], 1);
        atomicAdd(&I[IH_S2 + s2[e]], 1);
        atomicAdd(&I[IH_D2 + d2[e]], 1);
    }
}

// blocks 0,1: exclusive scan of dst histograms; blocks 2..65: deg rsqrt
__global__ __launch_bounds__(256) void k_scan(int* __restrict__ I, float* __restrict__ deg)
{
    int b = blockIdx.x;
    int t = threadIdx.x;
    if (b >= 2) {
        int i = (b - 2) * 256 + t;
        deg[i] = rsqrtf(fmaxf((float)I[i], 1.0f));
        return;
    }
    const int* hist = I + (b ? IH_D2 : IH_D1);
    int* offs = I + (b ? IO_F2 : IO_F1);
    int* cur  = I + (b ? IC_2 : IC_1);
    __shared__ int part[256];
    int base = t * 16;
    int loc[16];
    int s = 0;
#pragma unroll
    for (int i = 0; i < 16; ++i) { loc[i] = s; s += hist[base + i]; }
    part[t] = s;
    __syncthreads();
    if (t == 0) {
        int a = 0;
        for (int i = 0; i < 256; ++i) { int v = part[i]; part[i] = a; a += v; }
        offs[NN] = a;
    }
    __syncthreads();
    int p = part[t];
#pragma unroll
    for (int i = 0; i < 16; ++i) { offs[base + i] = p + loc[i]; cur[base + i] = p + loc[i]; }
}

__global__ __launch_bounds__(256) void k_fill(const int* __restrict__ s1, const int* __restrict__ d1,
                                              const int* __restrict__ s2, const int* __restrict__ d2,
                                              int* __restrict__ I)
{
    int e = blockIdx.x * 256 + threadIdx.x;
    if (e < EE) {
        int p1 = atomicAdd(&I[IC_1 + d1[e]], 1);
        I[IE_1 + p1] = s1[e];
        int p2 = atomicAdd(&I[IC_2 + d2[e]], 1);
        I[IE_2 + p2] = s2[e];
    }
}

// ---------------- all weight conversions in one launch ----------------
__global__ __launch_bounds__(256) void k_cvt_all(const float* __restrict__ w1, u16* __restrict__ w1o,
                                                 const float* __restrict__ ip, u16* __restrict__ ipo,
                                                 const float* __restrict__ op, u16* __restrict__ opo,
                                                 const float* __restrict__ f1, u16* __restrict__ f1o,
                                                 const float* __restrict__ f2, u16* __restrict__ f2o,
                                                 const float* __restrict__ w2, u16* __restrict__ w2o)
{
    int i8 = (blockIdx.x * 256 + threadIdx.x) * 8;
    const float* s; u16* d; int off;
    if      (i8 < CV1) { s = w1; d = w1o; off = i8; }
    else if (i8 < CV2) { s = ip; d = ipo; off = i8 - CV1; }
    else if (i8 < CV3) { s = op; d = opo; off = i8 - CV2; }
    else if (i8 < CV4) { s = f1; d = f1o; off = i8 - CV3; }
    else if (i8 < CV5) { s = f2; d = f2o; off = i8 - CV4; }
    else if (i8 < CV6) { s = w2; d = w2o; off = i8 - CV5; }
    else return;
    float4 a = *(const float4*)&s[off];
    float4 b = *(const float4*)&s[off + 4];
    uint4 o;
    o.x = (u32)f2b(a.x) | ((u32)f2b(a.y) << 16);
    o.y = (u32)f2b(a.z) | ((u32)f2b(a.w) << 16);
    o.z = (u32)f2b(b.x) | ((u32)f2b(b.y) << 16);
    o.w = (u32)f2b(b.z) | ((u32)f2b(b.w) << 16);
    *(uint4*)&d[off] = o;
}

// ---------------- row scale -> bf16 out (stacked 2-graph) ----------------
__global__ __launch_bounds__(256) void k_scale_bf(const float* __restrict__ in1, const float* __restrict__ in2,
                                                  const float* __restrict__ sc1, const float* __restrict__ sc2,
                                                  u16* __restrict__ out, int ncol)
{
    int quads = ncol >> 2;
    long long idx = (long long)blockIdx.x * 256 + threadIdx.x;
    if (idx >= (long long)NS * quads) return;
    int r  = (int)(idx / quads);
    int cq = (int)(idx % quads) * 4;
    const float* in; const float* sc; int rr;
    if (r < NN) { in = in1; sc = sc1; rr = r; } else { in = in2; sc = sc2; rr = r - NN; }
    float4 v = *(const float4*)&in[(size_t)rr * ncol + cq];
    float s = sc[rr];
    uint2 o;
    o.x = (u32)f2b(v.x * s) | ((u32)f2b(v.y * s) << 16);
    o.y = (u32)f2b(v.z * s) | ((u32)f2b(v.w * s) << 16);
    *(uint2*)&out[(size_t)r * ncol + cq] = o;
}

// ---------------- bf16 MFMA GEMM (m97 structure: global_load_lds width-16, 2 barriers/K-step) ----
// BN=128: 4 waves as 2x2 (64x64 each); BN=64: 4 waves as 4x1 (32x64 each).
// qcols: columns < qcols are scaled by SCL in the epilogue (qkv GEMM q-part).
template<int BN>
__global__ __launch_bounds__(256) void k_gemm_bf(const u16* __restrict__ A, const u16* __restrict__ W,
                                                 const float* __restrict__ bias, float* __restrict__ Cf,
                                                 u16* __restrict__ Cb, int M, int N, int K, int relu,
                                                 int qcols)
{
    constexpr int RM = (BN == 128) ? 4 : 2;   // row frags per wave
    __shared__ u16 As[128 * 32];
    __shared__ u16 Bs[BN * 32];
    int t = threadIdx.x;
    int w = t >> 6, L = t & 63;
    int lm = L & 15, lq = L >> 4;
    int wr = (BN == 128) ? (w >> 1) : w;
    int wc = (BN == 128) ? (w & 1) : 0;
    int row0 = blockIdx.y * 128, col0 = blockIdx.x * BN;
    f32x4 acc[RM][4];
#pragma unroll
    for (int i = 0; i < RM; ++i)
#pragma unroll
        for (int j = 0; j < 4; ++j) acc[i][j] = (f32x4){0.f, 0.f, 0.f, 0.f};

    // glds sources: instr j covers LDS rows (w*2+j)*16 + L/4, col-elems (L&3)*8
    const u16* As0 = &A[(size_t)(row0 + (w * 2) * 16 + (L >> 2)) * K + (L & 3) * 8];
    const u16* As1 = As0 + (size_t)16 * K;
    const u16* Bs0 = &W[(size_t)(col0 + ((BN == 128) ? (w * 2) * 16 : w * 16) + (L >> 2)) * K + (L & 3) * 8];
    const u16* Bs1 = Bs0 + (size_t)16 * K;
    u16* AsW = &As[(w * 2) * 512];
    u16* BsW = (BN == 128) ? &Bs[(w * 2) * 512] : &Bs[w * 512];

    for (int k0 = 0; k0 < K; k0 += 32) {
        if (k0) __syncthreads();   // all reads of previous tile done
        __builtin_amdgcn_global_load_lds((const GAS void*)(As0 + k0), (LAS void*)(LAS char*)AsW, 16, 0, 0);
        __builtin_amdgcn_global_load_lds((const GAS void*)(As1 + k0), (LAS void*)((LAS char*)AsW + 1024), 16, 0, 0);
        __builtin_amdgcn_global_load_lds((const GAS void*)(Bs0 + k0), (LAS void*)(LAS char*)BsW, 16, 0, 0);
        if constexpr (BN == 128)
            __builtin_amdgcn_global_load_lds((const GAS void*)(Bs1 + k0), (LAS void*)((LAS char*)BsW + 1024), 16, 0, 0);
        __syncthreads();           // vmcnt drained -> tile in LDS
        bf16x8 af[RM], bw[4];
#pragma unroll
        for (int i = 0; i < RM; ++i)
            af[i] = *(const bf16x8*)&As[(wr * (RM * 16) + i * 16 + lm) * 32 + lq * 8];
#pragma unroll
        for (int j = 0; j < 4; ++j)
            bw[j] = *(const bf16x8*)&Bs[(wc * 64 + j * 16 + lm) * 32 + lq * 8];
#pragma unroll
        for (int i = 0; i < RM; ++i)
#pragma unroll
            for (int j = 0; j < 4; ++j)
                acc[i][j] = MFMA16(af[i], bw[j], acc[i][j]);
    }

#pragma unroll
    for (int i = 0; i < RM; ++i) {
        int row = row0 + wr * (RM * 16) + i * 16 + lq * 4;
#pragma unroll
        for (int j = 0; j < 4; ++j) {
            int col = col0 + wc * 64 + j * 16 + lm;
            float bv = bias ? bias[col] : 0.0f;
            float cs = (col < qcols) ? SCL : 1.0f;
#pragma unroll
            for (int r = 0; r < 4; ++r) {
                float v = acc[i][j][r] + bv;
                if (relu) v = fmaxf(v, 0.0f);
                v *= cs;
                size_t off = (size_t)(row + r) * N + col;
                if (Cb) Cb[off] = f2b(v);
                else    Cf[off] = v;
            }
        }
    }
}

// ---------------- CSR gather (bf16 in) + GC finalize ----------------
__global__ __launch_bounds__(256) void k_gather_bf(const u16* __restrict__ hp, const int* __restrict__ I,
                                                   const float* __restrict__ din1, const float* __restrict__ din2,
                                                   const float* __restrict__ bias,
                                                   float* __restrict__ xout, u16* __restrict__ xb)
{
    int r = blockIdx.x, c = threadIdx.x;
    int g = r >> 12, rl = r & (NN - 1);
    const int* off = I + (g ? IO_F2 : IO_F1);
    const int* eid = I + (g ? IE_2 : IE_1);
    int beg = off[rl], end = off[rl + 1];
    const u16* base = hp + ((size_t)g << 12) * NHID;
    float a0 = 0.f, a1 = 0.f;
    for (int i = beg; i < end; ++i) {
        u32 v = ((const u32*)(base + (size_t)eid[i] * NHID))[c];
        a0 += b_lo(v);
        a1 += b_hi(v);
    }
    float s = (g ? din2 : din1)[rl];
    float2 bv = *(const float2*)&bias[c * 2];
    float v0 = fmaxf(fmaf(a0, s, bv.x), 0.f);
    float v1 = fmaxf(fmaf(a1, s, bv.y), 0.f);
    size_t o = (size_t)r * NHID + c * 2;
    if (xout) *(float2*)&xout[o] = make_float2(v0, v1);
    if (xb) *(u32*)&xb[o] = (u32)f2b(v0) | ((u32)f2b(v1) << 16);
}

// ---------------- V transpose (keys written in kappa order within each 64-tile) ----------------
// kappa = (key&15)*4 + (key>>4)  <=>  key = (kappa&3)*16 + (kappa>>2)
__global__ __launch_bounds__(256) void k_vtrans(const u16* __restrict__ qkvb, u16* __restrict__ vtb)
{
    __shared__ u16 tile[64][65];
    int t = threadIdx.x;
    int kt = blockIdx.x, h = blockIdx.y, g = blockIdx.z;
    int k0 = kt * 64;
    size_t gbase = (size_t)g * NN;
#pragma unroll
    for (int p = 0; p < 4; ++p) {
        int kl = p * 16 + (t >> 4);
        int d  = (t & 15) * 4;
        uint2 v = *(const uint2*)&qkvb[(gbase + k0 + kl) * 1536 + 1024 + h * 64 + d];
        tile[kl][d + 0] = (u16)(v.x & 0xffff);
        tile[kl][d + 1] = (u16)(v.x >> 16);
        tile[kl][d + 2] = (u16)(v.y & 0xffff);
        tile[kl][d + 3] = (u16)(v.y >> 16);
    }
    __syncthreads();
#pragma unroll
    for (int p = 0; p < 4; ++p) {
        int dl = p * 16 + (t >> 4);
        int kap = (t & 15) * 4;           // kappa base; kappa+e -> local key e*16 + (t&15)
        u16 v0 = tile[(t & 15) + 0][dl];
        u16 v1 = tile[(t & 15) + 16][dl];
        u16 v2 = tile[(t & 15) + 32][dl];
        u16 v3 = tile[(t & 15) + 48][dl];
        uint2 o;
        o.x = (u32)v0 | ((u32)v1 << 16);
        o.y = (u32)v2 | ((u32)v3 << 16);
        *(uint2*)&vtb[((size_t)(g * 8 + h) * 64 + dl) * (size_t)NN + k0 + kap] = o;
    }
}

// ---------------- MFMA flash attention v7 ----------------
// 4 waves/block, 16 q-rows/wave, 64-key tiles, double-buffered global_load_lds.
// -m folded into QK^T MFMA C-operand (no per-element subtract); max3-chain
// deferred-max check; all LDS rows 128B, (row&7)<<4 XOR swizzle; kappa keys.
__global__ __launch_bounds__(256, 4) void k_attn(const u16* __restrict__ qkv,
                                                 const u16* __restrict__ vt,
                                                 u16* __restrict__ ctb)
{
    __shared__ __align__(16) u16 Kl[2][64 * 64];   // [rho][d]   rho holds key perm(rho)
    __shared__ __align__(16) u16 Vl[2][64 * 64];   // [d][kappa]
    __shared__ __align__(16) u16 Pl[4][16 * 64];   // per-wave [q][kappa]
    int t = threadIdx.x;
    int w = t >> 6, L = t & 63;
    int lm = L & 15, lq = L >> 4;
    int qt = blockIdx.x, h = blockIdx.y, g = blockIdx.z;
    size_t gbase = (size_t)g * NN;
    int q0 = qt * 64 + w * 16;

    const u16* kbase = &qkv[gbase * 1536 + 512 + h * 64];
    const u16* vbase = &vt[(size_t)(g * 8 + h) * 64 * (size_t)NN];

    // staging: instr j covers LDS rows rho = (w*2+j)*8 + L/8, byte (L&7)*16 ^ (rho&7)<<4
    int srcb = ((L & 7) * 16) ^ ((L >> 3) << 4);          // (rho&7) == L>>3
    int rho0 = (w * 2) * 8 + (L >> 3);
    int rho1 = rho0 + 8;
    int kp0 = (rho0 & 15) * 4 + (rho0 >> 4);              // perm(rho): global key row
    int kp1 = (rho1 & 15) * 4 + (rho1 >> 4);
    const u16* kg0 = &kbase[(size_t)kp0 * 1536 + (srcb >> 1)];
    const u16* kg1 = &kbase[(size_t)kp1 * 1536 + (srcb >> 1)];
    const u16* vg0 = &vbase[(size_t)rho0 * NN + (srcb >> 1)];
    const u16* vg1 = &vbase[(size_t)rho1 * NN + (srcb >> 1)];
    u16* Pw = &Pl[w][0];

    // Q A-frags (16 rows; q pre-scaled by SCL in qkv GEMM)
    const u16* qp = &qkv[(gbase + q0 + lm) * 1536 + h * 64 + lq * 8];
    bf16x8 qa0 = *(const bf16x8*)qp;
    bf16x8 qa1 = *(const bf16x8*)(qp + 32);

    f32x4 ctx[4];
#pragma unroll
    for (int n = 0; n < 4; ++n) ctx[n] = (f32x4){0.f, 0.f, 0.f, 0.f};
    float m[4], lsum[4];
#pragma unroll
    for (int r = 0; r < 4; ++r) { m[r] = 0.0f; lsum[r] = 0.0f; }

    // hoisted P-write addresses (tile-invariant)
    uint2* pwa[4];
#pragma unroll
    for (int r = 0; r < 4; ++r) {
        int row = lq * 4 + r;
        pwa[r] = (uint2*)((char*)Pw + row * 128 + ((lm * 8) ^ ((row & 7) << 4)));
    }

    // prologue: stage tile 0 into buf 0
    __builtin_amdgcn_global_load_lds((const GAS void*)kg0, (LAS void*)((LAS char*)&Kl[0][0] + (w * 2) * 1024), 16, 0, 0);
    __builtin_amdgcn_global_load_lds((const GAS void*)kg1, (LAS void*)((LAS char*)&Kl[0][0] + (w * 2 + 1) * 1024), 16, 0, 0);
    __builtin_amdgcn_global_load_lds((const GAS void*)vg0, (LAS void*)((LAS char*)&Vl[0][0] + (w * 2) * 1024), 16, 0, 0);
    __builtin_amdgcn_global_load_lds((const GAS void*)vg1, (LAS void*)((LAS char*)&Vl[0][0] + (w * 2 + 1) * 1024), 16, 0, 0);
    __syncthreads();

    int cur = 0;
    for (int t0 = 0; t0 < NN; t0 += 64) {
        if (t0 + 64 < NN) {
            size_t ko = (size_t)(t0 + 64) * 1536;
            __builtin_amdgcn_global_load_lds((const GAS void*)(kg0 + ko), (LAS void*)((LAS char*)&Kl[cur ^ 1][0] + (w * 2) * 1024), 16, 0, 0);
            __builtin_amdgcn_global_load_lds((const GAS void*)(kg1 + ko), (LAS void*)((LAS char*)&Kl[cur ^ 1][0] + (w * 2 + 1) * 1024), 16, 0, 0);
            __builtin_amdgcn_global_load_lds((const GAS void*)(vg0 + t0 + 64), (LAS void*)((LAS char*)&Vl[cur ^ 1][0] + (w * 2) * 1024), 16, 0, 0);
            __builtin_amdgcn_global_load_lds((const GAS void*)(vg1 + t0 + 64), (LAS void*)((LAS char*)&Vl[cur ^ 1][0] + (w * 2 + 1) * 1024), 16, 0, 0);
        }
        const char* Kc = (const char*)&Kl[cur][0];
        const char* Vc = (const char*)&Vl[cur][0];
        int sw = (lm & 7) << 4;

        // QK^T with C-init = -m (s = score - m directly, exp2 units)
        f32x4 minit = (f32x4){-m[0], -m[1], -m[2], -m[3]};
        f32x4 s[4];
        __builtin_amdgcn_s_setprio(1);
#pragma unroll
        for (int kc = 0; kc < 4; ++kc) {
            const char* rp = Kc + (kc * 16 + lm) * 128;
            bf16x8 kb0 = *(const bf16x8*)(rp + ((lq * 16) ^ sw));
            bf16x8 kb1 = *(const bf16x8*)(rp + ((64 + lq * 16) ^ sw));
            f32x4 z = MFMA16(qa0, kb0, minit);
            z = MFMA16(qa1, kb1, z);
            s[kc] = z;
        }
        __builtin_amdgcn_s_setprio(0);

        // deferred-max check (max3 chains)
        float amax[4];
#pragma unroll
        for (int r = 0; r < 4; ++r)
            amax[r] = fmaxf(fmaxf(fmaxf(s[0][r], s[1][r]), s[2][r]), s[3][r]);
        float dmax = fmaxf(fmaxf(fmaxf(amax[0], amax[1]), amax[2]), amax[3]);
        if (__any(dmax > THR)) {
#pragma unroll
            for (int r = 0; r < 4; ++r) {
                float mr = amax[r];
                mr = fmaxf(mr, __shfl_xor(mr, 1));
                mr = fmaxf(mr, __shfl_xor(mr, 2));
                mr = fmaxf(mr, __shfl_xor(mr, 4));
                mr = fmaxf(mr, __shfl_xor(mr, 8));
                float dm = fmaxf(mr, 0.0f);
                m[r] += dm;
                float corr = exp2f(-dm);
                lsum[r] *= corr;
#pragma unroll
                for (int n = 0; n < 4; ++n) ctx[n][r] *= corr;
#pragma unroll
                for (int kc = 0; kc < 4; ++kc) s[kc][r] -= dm;
            }
        }
        // fast path: exp2 directly (no subtract), per-lane l partial, packed P -> LDS
#pragma unroll
        for (int r = 0; r < 4; ++r) {
            float p0 = exp2f(s[0][r]);
            float p1 = exp2f(s[1][r]);
            float p2 = exp2f(s[2][r]);
            float p3 = exp2f(s[3][r]);
            lsum[r] += (p0 + p1) + (p2 + p3);
            __hip_bfloat162 c0 = __float22bfloat162_rn(make_float2(p0, p1));
            __hip_bfloat162 c1 = __float22bfloat162_rn(make_float2(p2, p3));
            uint2 pv;
            pv.x = *(u32*)&c0;
            pv.y = *(u32*)&c1;
            *pwa[r] = pv;
        }

        // PV over kappa-ordered keys
        __builtin_amdgcn_s_setprio(1);
        {
            const char* pr = (const char*)Pw + lm * 128;
            bf16x8 pa0 = *(const bf16x8*)(pr + ((lq * 16) ^ sw));
            bf16x8 pa1 = *(const bf16x8*)(pr + ((64 + lq * 16) ^ sw));
#pragma unroll
            for (int n = 0; n < 4; ++n) {
                const char* vr = Vc + (n * 16 + lm) * 128;
                bf16x8 vb0 = *(const bf16x8*)(vr + ((lq * 16) ^ sw));
                bf16x8 vb1 = *(const bf16x8*)(vr + ((64 + lq * 16) ^ sw));
                ctx[n] = MFMA16(pa0, vb0, ctx[n]);
                ctx[n] = MFMA16(pa1, vb1, ctx[n]);
            }
        }
        __builtin_amdgcn_s_setprio(0);

        __syncthreads();   // drains prefetch (vmcnt0) + LDS reuse fence
        cur ^= 1;
    }

    // epilogue
    float inv[4];
#pragma unroll
    for (int r = 0; r < 4; ++r) {
        float lr = lsum[r];
        lr += __shfl_xor(lr, 1);
        lr += __shfl_xor(lr, 2);
        lr += __shfl_xor(lr, 4);
        lr += __shfl_xor(lr, 8);
        inv[r] = 1.0f / lr;
    }
#pragma unroll
    for (int n = 0; n < 4; ++n)
#pragma unroll
        for (int r = 0; r < 4; ++r) {
            int row = q0 + lq * 4 + r;
            int col = h * 64 + n * 16 + lm;
            ctb[(gbase + row) * NHID + col] = f2b(ctx[n][r] * inv[r]);
        }
}

// ---------------- fused residual-add + LayerNorm (+optional row-scale) + bf16 out ----------------
__global__ __launch_bounds__(256) void k_add_ln(const float* __restrict__ x, const float* __restrict__ y,
                                                const float* __restrict__ g, const float* __restrict__ bb,
                                                float* __restrict__ xout, u16* __restrict__ xb,
                                                const float* __restrict__ sc1, const float* __restrict__ sc2)
{
    int r = blockIdx.x, tid = threadIdx.x;
    int c = tid * 2;
    float2 xv = *(const float2*)&x[(size_t)r * NHID + c];
    float2 yv = *(const float2*)&y[(size_t)r * NHID + c];
    float a0 = xv.x + yv.x, a1 = xv.y + yv.y;
    float s = a0 + a1;
    float qs = a0 * a0 + a1 * a1;
#pragma unroll
    for (int off = 32; off > 0; off >>= 1) {
        s  += __shfl_xor(s, off);
        qs += __shfl_xor(qs, off);
    }
    __shared__ float ss[4], qq[4];
    int w = tid >> 6;
    if ((tid & 63) == 0) { ss[w] = s; qq[w] = qs; }
    __syncthreads();
    s  = ss[0] + ss[1] + ss[2] + ss[3];
    qs = qq[0] + qq[1] + qq[2] + qq[3];
    float mu  = s * (1.0f / NHID);
    float var = qs * (1.0f / NHID) - mu * mu;
    float rs = rsqrtf(var + 1e-5f);
    float2 gv = *(const float2*)&g[c];
    float2 bv = *(const float2*)&bb[c];
    float o0 = (a0 - mu) * rs * gv.x + bv.x;
    float o1 = (a1 - mu) * rs * gv.y + bv.y;
    if (xout) *(float2*)&xout[(size_t)r * NHID + c] = make_float2(o0, o1);
    float sc = 1.0f;
    if (sc1) sc = (r < NN) ? sc1[r] : sc2[r - NN];
    u32 o = (u32)f2b(o0 * sc) | ((u32)f2b(o1 * sc) << 16);
    *(u32*)&xb[(size_t)r * NHID + c] = o;
}

// ---------------- per-segment mean ----------------
__global__ __launch_bounds__(512) void k_seg_mean(const float* __restrict__ h, float* __restrict__ means)
{
    int b = blockIdx.x;
    int st = blockIdx.y;
    int col = threadIdx.x;
    const float* hp = &h[((size_t)st * NN + (size_t)b * 256) * NHID + col];
    float acc = 0.0f;
    for (int i = 0; i < 256; ++i) acc += hp[(size_t)i * NHID];
    means[((size_t)st * 16 + b) * NHID + col] = acc * (1.0f / 256.0f);
}

// ---------------- MLP head + softmax ----------------
__global__ __launch_bounds__(256) void k_head(const float* __restrict__ means,
                                              const float* __restrict__ l1w, const float* __restrict__ l1b,
                                              const float* __restrict__ l2w, const float* __restrict__ l2b,
                                              const float* __restrict__ l3w, const float* __restrict__ l3b,
                                              float* __restrict__ out)
{
    __shared__ float hg[512];
    __shared__ float t1[512];
    __shared__ float t2[128];
    int b = blockIdx.x;
    int t = threadIdx.x;
    hg[t]       = means[b * 512 + t]       * means[(16 + b) * 512 + t];
    hg[t + 256] = means[b * 512 + t + 256] * means[(16 + b) * 512 + t + 256];
    __syncthreads();
#pragma unroll
    for (int o = t; o < 512; o += 256) {
        const float* wr = &l1w[(size_t)o * 512];
        float acc = l1b[o];
        for (int k = 0; k < 512; k += 4) {
            float4 w = *(const float4*)&wr[k];
            acc = fmaf(hg[k], w.x, acc);
            acc = fmaf(hg[k + 1], w.y, acc);
            acc = fmaf(hg[k + 2], w.z, acc);
            acc = fmaf(hg[k + 3], w.w, acc);
        }
        t1[o] = acc;
    }
    __syncthreads();
    if (t < 128) {
        const float* wr = &l2w[(size_t)t * 512];
        float acc = l2b[t];
        for (int k = 0; k < 512; k += 4) {
            float4 w = *(const float4*)&wr[k];
            acc = fmaf(t1[k], w.x, acc);
            acc = fmaf(t1[k + 1], w.y, acc);
            acc = fmaf(t1[k + 2], w.z, acc);
            acc = fmaf(t1[k + 3], w.w, acc);
        }
        t2[t] = acc;
    }
    __syncthreads();
    if (t < 64) {
        float p0 = t2[t] * l3w[t] + t2[t + 64] * l3w[t + 64];
        float p1 = t2[t] * l3w[128 + t] + t2[t + 64] * l3w[128 + t + 64];
#pragma unroll
        for (int off = 32; off > 0; off >>= 1) {
            p0 += __shfl_xor(p0, off);
            p1 += __shfl_xor(p1, off);
        }
        if (t == 0) {
            float v0 = p0 + l3b[0], v1 = p1 + l3b[1];
            float mx = fmaxf(v0, v1);
            float e0 = __expf(v0 - mx), e1 = __expf(v1 - mx);
            float inv = 1.0f / (e0 + e1);
            out[b * 2 + 0] = e0 * inv;
            out[b * 2 + 1] = e1 * inv;
        }
    }
}

// ---------------- launch ----------------
extern "C" void kernel_launch(void* const* d_in, const int* in_sizes, int n_in,
                              void* d_out, int out_size, void* d_ws, size_t ws_size,
                              hipStream_t stream)
{
    const float* fea1 = (const float*)d_in[0];
    const float* fea2 = (const float*)d_in[1];
    const int* src1 = (const int*)d_in[2];
    const int* dst1 = (const int*)d_in[3];
    const int* src2 = (const int*)d_in[4];
    const int* dst2 = (const int*)d_in[5];
    const float* W1 = (const float*)d_in[9];
    const float* b1 = (const float*)d_in[10];
    const float* W2 = (const float*)d_in[11];
    const float* b2 = (const float*)d_in[12];
    const float* in_proj_w = (const float*)d_in[13];
    const float* in_proj_b = (const float*)d_in[14];
    const float* out_proj_w = (const float*)d_in[15];
    const float* out_proj_b = (const float*)d_in[16];
    const float* ln1_g = (const float*)d_in[17];
    const float* ln1_b = (const float*)d_in[18];
    const float* ln2_g = (const float*)d_in[19];
    const float* ln2_b = (const float*)d_in[20];
    const float* ff1_w = (const float*)d_in[21];
    const float* ff1_b = (const float*)d_in[22];
    const float* ff2_w = (const float*)d_in[23];
    const float* ff2_b = (const float*)d_in[24];
    const float* l1_w = (const float*)d_in[25];
    const float* l1_b = (const float*)d_in[26];
    const float* l2_w = (const float*)d_in[27];
    const float* l2_b = (const float*)d_in[28];
    const float* l3_w = (const float*)d_in[29];
    const float* l3_b = (const float*)d_in[30];

    float* ws = (float*)d_ws;
    u16*  Ab   = (u16*)(ws + OFF_A);
    float* HP  = ws + OFF_HP;
    u16*  HPb  = (u16*)(ws + OFF_HP);
    float* X   = ws + OFF_X;
    u16*  Xb   = (u16*)(ws + OFF_XB);
    u16*  QKVb = (u16*)(ws + OFF_E);
    float* AG2 = ws + OFF_E;
    u16*  Vtb  = (u16*)(ws + OFF_VT);
    u16*  CTb  = (u16*)(ws + OFF_CTB);
    u16*  W1b  = (u16*)(ws + OFF_W1B);
    u16*  IPb  = (u16*)(ws + OFF_IPB);
    u16*  OPb  = (u16*)(ws + OFF_OPB);
    u16*  F1b  = (u16*)(ws + OFF_F1B);
    u16*  F2b  = (u16*)(ws + OFF_F2B);
    u16*  W2b  = (u16*)(ws + OFF_W2B);
    float* ME  = ws + OFF_ME;
    float* DG  = ws + OFF_DG;
    int*   I   = (int*)(ws + OFF_INT);
    float* dout1 = DG;
    float* din1  = DG + NN;
    float* dout2 = DG + 2 * NN;
    float* din2  = DG + 3 * NN;

    hipMemsetAsync(I, 0, 4 * NN * sizeof(int), stream);

    // CSR build + degrees (deg rsqrt folded into k_scan blocks >= 2)
    k_hist<<<EE / 256, 256, 0, stream>>>(src1, dst1, src2, dst2, I);
    k_scan<<<2 + 64, 256, 0, stream>>>(I, DG);
    k_fill<<<EE / 256, 256, 0, stream>>>(src1, dst1, src2, dst2, I);

    // all weight conversions in one launch
    k_cvt_all<<<CV6 / 8 / 256, 256, 0, stream>>>(W1, W1b, in_proj_w, IPb, out_proj_w, OPb,
                                                 ff1_w, F1b, ff2_w, F2b, W2, W2b);

    // GC1: scale -> gemm (bf16 out) -> CSR gather
    {
        long long tq = (long long)NS * (NFEAT / 4);
        k_scale_bf<<<(int)((tq + 255) / 256), 256, 0, stream>>>(fea1, fea2, dout1, dout2, Ab, NFEAT);
    }
    k_gemm_bf<64><<<dim3(NHID / 64, NS / 128), 256, 0, stream>>>(Ab, W1b, nullptr, nullptr, HPb, NS, NHID, NFEAT, 0, 0);
    k_gather_bf<<<NS, 256, 0, stream>>>(HPb, I, din1, din2, b1, X, Xb);

    // encoder (q-part of qkv pre-scaled by SCL in the GEMM epilogue)
    k_gemm_bf<128><<<dim3(1536 / 128, NS / 128), 256, 0, stream>>>(Xb, IPb, in_proj_b, nullptr, QKVb, NS, 1536, NHID, 0, NHID);
    k_vtrans<<<dim3(NN / 64, 8, 2), 256, 0, stream>>>(QKVb, Vtb);
    k_attn<<<dim3(NN / 64, 8, 2), 256, 0, stream>>>(QKVb, Vtb, CTb);
    k_gemm_bf<64><<<dim3(NHID / 64, NS / 128), 256, 0, stream>>>(CTb, OPb, out_proj_b, HP, nullptr, NS, NHID, NHID, 0, 0);
    k_add_ln<<<NS, 256, 0, stream>>>(X, HP, ln1_g, ln1_b, X, Xb, nullptr, nullptr);
    k_gemm_bf<128><<<dim3(DFF / 128, NS / 128), 256, 0, stream>>>(Xb, F1b, ff1_b, nullptr, Ab, NS, DFF, NHID, 1, 0);
    k_gemm_bf<64><<<dim3(NHID / 64, NS / 128), 256, 0, stream>>>(Ab, F2b, ff2_b, HP, nullptr, NS, NHID, DFF, 0, 0);
    // LN2 fused with GC2 pre-scale
    k_add_ln<<<NS, 256, 0, stream>>>(X, HP, ln2_g, ln2_b, nullptr, Ab, dout1, dout2);

    // GC2
    k_gemm_bf<64><<<dim3(NHID / 64, NS / 128), 256, 0, stream>>>(Ab, W2b, nullptr, nullptr, HPb, NS, NHID, NHID, 0, 0);
    k_gather_bf<<<NS, 256, 0, stream>>>(HPb, I, din1, din2, b2, AG2, nullptr);

    // readout
    k_seg_mean<<<dim3(16, 2), 512, 0, stream>>>(AG2, ME);
    k_head<<<16, 256, 0, stream>>>(ME, l1_w, l1_b, l2_w, l2_b, l3_w, l3_b, (float*)d_out);
}